// Round 5
// baseline (357.503 us; speedup 1.0000x reference)
//
#include <hip/hip_runtime.h>

// instant-NGP hash-grid encoder, 12 levels, F=2, N = 1<<20 points.
// Levels 0-4 dense (R^3 <= 2^19), levels 5-11 hashed (table = 2^19 entries = 4 MB).
//
// R2 structure: one pass per hashed level (gridDim.y, x-major dispatch => one
// 4 MB table per XCD-L2 window), staging to ws [7][N] float2; merge kernel does
// dense levels + coalesced ws gather + float4 stores.
// R4: hashed corner pairing (even ix: dx=0/1 pair sits in one 16B-aligned
//     float4, possibly swapped) -> ~25% fewer table requests. Measured win.
// R5: merge kernel reverted to R2-known-good form (R4's paired dense loads +
//     NT hints regressed it 137->182 us). Pass 1: NT loads for x so the
//     read-once stream doesn't evict table lines from the 4 MB XCD-L2
//     (FETCH_SIZE showed 344 MB vs 28 MB compulsory).

#define N_LEVELS 12
#define N_HASHED 7

typedef float f4a16 __attribute__((ext_vector_type(4), aligned(16)));
typedef float f2v   __attribute__((ext_vector_type(2)));

__device__ __forceinline__ void trilinear_setup(float p, int r, float* w, unsigned* i0)
{
    float f  = p * (float)(r - 1);
    float f0 = fminf(fmaxf(floorf(f), 0.0f), (float)(r - 2));
    float w1 = f - f0;
    w[0] = 1.0f - w1;
    w[1] = w1;
    *i0 = (unsigned)f0;
}

// ---------------- pass 1: hashed levels (5..11), one level per blockIdx.y ----
__global__ __launch_bounds__(256) void hashed_levels_kernel(
    const float* __restrict__ x,
    const float* __restrict__ params,
    float* __restrict__ ws,   // [N_HASHED][N] float2, as raw floats
    int N)
{
    constexpr int      HRES[N_HASHED] = {92, 128, 184, 256, 368, 512, 736};
    constexpr unsigned HOFF[N_HASHED] = {408512u, 932800u, 1457088u, 1981376u,
                                         2505664u, 3029952u, 3554240u};
    constexpr unsigned HASH_MASK = 524287u;   // 2^19 - 1
    constexpr unsigned P1 = 2654435761u;
    constexpr unsigned P2 = 805459861u;

    const int n = blockIdx.x * blockDim.x + threadIdx.x;
    if (n >= N) return;
    const int li = blockIdx.y;          // 0..6 -> level 5+li

    // NT: x is a read-once stream per dispatch; keep it out of L2 so the
    // 4 MB hash table stays resident.
    const float px = __builtin_nontemporal_load(x + 3 * n + 0);
    const float py = __builtin_nontemporal_load(x + 3 * n + 1);
    const float pz = __builtin_nontemporal_load(x + 3 * n + 2);

    const int r = HRES[li];
    float wx[2], wy[2], wz[2];
    unsigned ix, iy, iz;
    trilinear_setup(px, r, wx, &ix);
    trilinear_setup(py, r, wy, &iy);
    trilinear_setup(pz, r, wz, &iz);

    const float* __restrict__ tabf = params + 2u * (size_t)HOFF[li];

    const unsigned hy[2] = {iy * P1, (iy + 1u) * P1};
    const unsigned hz[2] = {iz * P2, (iz + 1u) * P2};

    float s0 = 0.0f, s1 = 0.0f;

    if ((ix & 1u) == 0u) {
        // even ix: corner pair (dx=0,dx=1) = {a, a^1} -> one aligned float4
#pragma unroll
        for (int p = 0; p < 4; ++p) {
            const unsigned dy = p & 1, dz = (p >> 1) & 1;
            const unsigned h = hy[dy] ^ hz[dz];
            const unsigned a = (ix ^ h) & HASH_MASK;      // corner dx=0
            const unsigned sw = a & 1u;                   // 1 -> pair stored (c1,c0)
            const f4a16 q = *(const f4a16*)(tabf + 2u * (a & ~1u));
            const float f0x = sw ? q.z : q.x;
            const float f0y = sw ? q.w : q.y;
            const float f1x = sw ? q.x : q.z;
            const float f1y = sw ? q.y : q.w;
            const float wyz = wy[dy] * wz[dz];
            const float wc0 = wx[0] * wyz;
            const float wc1 = wx[1] * wyz;
            s0 = fmaf(wc0, f0x, s0);
            s1 = fmaf(wc0, f0y, s1);
            s0 = fmaf(wc1, f1x, s0);
            s1 = fmaf(wc1, f1y, s1);
        }
    } else {
        const unsigned hx[2] = {ix, ix + 1u};
#pragma unroll
        for (int c = 0; c < 8; ++c) {
            const unsigned dx = c & 1, dy = (c >> 1) & 1, dz = (c >> 2) & 1;
            const unsigned idx = (hx[dx] ^ hy[dy] ^ hz[dz]) & HASH_MASK;
            const float2 f = *(const float2*)(tabf + 2u * idx);
            const float wc = (wx[dx] * wy[dy]) * wz[dz];
            s0 = fmaf(wc, f.x, s0);
            s1 = fmaf(wc, f.y, s1);
        }
    }

    f2v v; v.x = s0; v.y = s1;
    __builtin_nontemporal_store(v, (f2v*)(ws + 2u * ((size_t)li * N + n)));
}

// ---------------- pass 2: dense levels (0..4) + merge (R2 known-good) -------
__global__ __launch_bounds__(256) void dense_merge_kernel(
    const float* __restrict__ x,
    const float* __restrict__ params,
    const float2* __restrict__ ws,   // [N_HASHED][N]
    float* __restrict__ out,
    int N)
{
    constexpr int      DRES[5] = {16, 23, 32, 46, 64};
    constexpr unsigned DOFF[5] = {0u, 4096u, 16264u, 49032u, 146368u};

    const int n = blockIdx.x * blockDim.x + threadIdx.x;
    if (n >= N) return;

    const float px = x[3 * n + 0];
    const float py = x[3 * n + 1];
    const float pz = x[3 * n + 2];

    float res[2 * N_LEVELS];

#pragma unroll
    for (int l = 0; l < 5; ++l) {
        const int r = DRES[l];
        float wx[2], wy[2], wz[2];
        unsigned ix, iy, iz;
        trilinear_setup(px, r, wx, &ix);
        trilinear_setup(py, r, wy, &iy);
        trilinear_setup(pz, r, wz, &iz);

        const float2* __restrict__ tab = (const float2*)params + DOFF[l];
        const unsigned rr = (unsigned)(r * r);
        const unsigned base = ix + iy * (unsigned)r + iz * rr;

        float s0 = 0.0f, s1 = 0.0f;
#pragma unroll
        for (int c = 0; c < 8; ++c) {
            const unsigned dx = c & 1, dy = (c >> 1) & 1, dz = (c >> 2) & 1;
            const unsigned idx = base + dx + dy * (unsigned)r + dz * rr;
            float2 f = tab[idx];
            float wc = (wx[dx] * wy[dy]) * wz[dz];
            s0 = fmaf(wc, f.x, s0);
            s1 = fmaf(wc, f.y, s1);
        }
        res[2 * l + 0] = s0;
        res[2 * l + 1] = s1;
    }

#pragma unroll
    for (int li = 0; li < N_HASHED; ++li) {
        float2 f = ws[(size_t)li * N + n];    // coalesced: stride-8B in n
        res[2 * (5 + li) + 0] = f.x;
        res[2 * (5 + li) + 1] = f.y;
    }

    float4* __restrict__ o4 = (float4*)(out + (size_t)n * 24);
#pragma unroll
    for (int k = 0; k < 6; ++k) {
        float4 v;
        v.x = res[4 * k + 0];
        v.y = res[4 * k + 1];
        v.z = res[4 * k + 2];
        v.w = res[4 * k + 3];
        o4[k] = v;
    }
}

// ---------------- fallback: fused single kernel -----------------------------
__global__ __launch_bounds__(256) void grid_encode_fused_kernel(
    const float* __restrict__ x,
    const float* __restrict__ params,
    float* __restrict__ out,
    int N)
{
    int n = blockIdx.x * blockDim.x + threadIdx.x;
    if (n >= N) return;

    const float px = x[3 * n + 0];
    const float py = x[3 * n + 1];
    const float pz = x[3 * n + 2];

    constexpr int   RES[N_LEVELS]    = {16, 23, 32, 46, 64, 92, 128, 184, 256, 368, 512, 736};
    constexpr unsigned OFF[N_LEVELS] = {0u, 4096u, 16264u, 49032u, 146368u, 408512u,
                                        932800u, 1457088u, 1981376u, 2505664u, 3029952u, 3554240u};
    constexpr unsigned HASH_MASK = 524287u;
    constexpr unsigned P1 = 2654435761u;
    constexpr unsigned P2 = 805459861u;

    float res[2 * N_LEVELS];

#pragma unroll
    for (int l = 0; l < N_LEVELS; ++l) {
        const int r = RES[l];
        float wx[2], wy[2], wz[2];
        unsigned ix, iy, iz;
        trilinear_setup(px, r, wx, &ix);
        trilinear_setup(py, r, wy, &iy);
        trilinear_setup(pz, r, wz, &iz);

        const float2* __restrict__ tab = (const float2*)params + OFF[l];
        float s0 = 0.0f, s1 = 0.0f;

        const bool dense = ((long long)r * r * r) <= (long long)524288;
        if (dense) {
            const unsigned rr = (unsigned)(r * r);
            const unsigned base = ix + iy * (unsigned)r + iz * rr;
#pragma unroll
            for (int c = 0; c < 8; ++c) {
                const unsigned dx = c & 1, dy = (c >> 1) & 1, dz = (c >> 2) & 1;
                const unsigned idx = base + dx + dy * (unsigned)r + dz * rr;
                float2 f = tab[idx];
                float wc = (wx[dx] * wy[dy]) * wz[dz];
                s0 = fmaf(wc, f.x, s0);
                s1 = fmaf(wc, f.y, s1);
            }
        } else {
            const unsigned hx[2] = {ix, ix + 1u};
            const unsigned hy[2] = {iy * P1, (iy + 1u) * P1};
            const unsigned hz[2] = {iz * P2, (iz + 1u) * P2};
#pragma unroll
            for (int c = 0; c < 8; ++c) {
                const unsigned dx = c & 1, dy = (c >> 1) & 1, dz = (c >> 2) & 1;
                const unsigned idx = (hx[dx] ^ hy[dy] ^ hz[dz]) & HASH_MASK;
                float2 f = tab[idx];
                float wc = (wx[dx] * wy[dy]) * wz[dz];
                s0 = fmaf(wc, f.x, s0);
                s1 = fmaf(wc, f.y, s1);
            }
        }
        res[2 * l + 0] = s0;
        res[2 * l + 1] = s1;
    }

    float4* __restrict__ o4 = (float4*)(out + (size_t)n * 24);
#pragma unroll
    for (int k = 0; k < 6; ++k) {
        float4 v;
        v.x = res[4 * k + 0];
        v.y = res[4 * k + 1];
        v.z = res[4 * k + 2];
        v.w = res[4 * k + 3];
        o4[k] = v;
    }
}

extern "C" void kernel_launch(void* const* d_in, const int* in_sizes, int n_in,
                              void* d_out, int out_size, void* d_ws, size_t ws_size,
                              hipStream_t stream) {
    const float* x      = (const float*)d_in[0];
    const float* params = (const float*)d_in[1];
    float* out          = (float*)d_out;

    const int N = in_sizes[0] / 3;  // 1<<20
    const int block = 256;
    const int gx = (N + block - 1) / block;

    const size_t ws_needed = (size_t)N_HASHED * (size_t)N * sizeof(float) * 2;  // 56 MB

    if (ws_size >= ws_needed) {
        float* ws = (float*)d_ws;
        dim3 grid1(gx, N_HASHED, 1);
        hashed_levels_kernel<<<grid1, block, 0, stream>>>(x, params, ws, N);
        dense_merge_kernel<<<gx, block, 0, stream>>>(x, params, (const float2*)ws, out, N);
    } else {
        grid_encode_fused_kernel<<<gx, block, 0, stream>>>(x, params, out, N);
    }
}

// Round 6
// 285.369 us; speedup vs baseline: 1.2528x; 1.2528x over previous
//
#include <hip/hip_runtime.h>

// instant-NGP hash-grid encoder, 12 levels, F=2, N = 1<<20 points.
// Levels 0-4 dense (R^3 <= 2^19), levels 5-11 hashed (table = 2^19 entries = 4 MB).
//
// R2 structure: one pass per hashed level (gridDim.y, x-major dispatch => one
// 4 MB table per XCD-L2 window), staging to ws [7][N] float2; merge kernel does
// dense levels + coalesced ws gather + float4 stores.
// R4: hashed corner pairing (even ix: dx=0/1 pair in one 16B float4) — win.
// R5 lesson: ALL non-temporal hints removed. ws/x are re-read by the next
//     kernel; NT pushed them out of L2/L3 and the merge paid 2x (137->205 us).
// R6: merge = R2 body + dense corner pairing (idx,idx+1 -> one unaligned 16B
//     load), no NT anywhere. Clean attribution for the pairing effect.

#define N_LEVELS 12
#define N_HASHED 7

typedef float f4a16 __attribute__((ext_vector_type(4), aligned(16)));
typedef float f4a8  __attribute__((ext_vector_type(4), aligned(8)));

__device__ __forceinline__ void trilinear_setup(float p, int r, float* w, unsigned* i0)
{
    float f  = p * (float)(r - 1);
    float f0 = fminf(fmaxf(floorf(f), 0.0f), (float)(r - 2));
    float w1 = f - f0;
    w[0] = 1.0f - w1;
    w[1] = w1;
    *i0 = (unsigned)f0;
}

// ---------------- pass 1: hashed levels (5..11), one level per blockIdx.y ----
__global__ __launch_bounds__(256) void hashed_levels_kernel(
    const float* __restrict__ x,
    const float* __restrict__ params,
    float2* __restrict__ ws,   // [N_HASHED][N]
    int N)
{
    constexpr int      HRES[N_HASHED] = {92, 128, 184, 256, 368, 512, 736};
    constexpr unsigned HOFF[N_HASHED] = {408512u, 932800u, 1457088u, 1981376u,
                                         2505664u, 3029952u, 3554240u};
    constexpr unsigned HASH_MASK = 524287u;   // 2^19 - 1
    constexpr unsigned P1 = 2654435761u;
    constexpr unsigned P2 = 805459861u;

    const int n = blockIdx.x * blockDim.x + threadIdx.x;
    if (n >= N) return;
    const int li = blockIdx.y;          // 0..6 -> level 5+li

    const float px = x[3 * n + 0];
    const float py = x[3 * n + 1];
    const float pz = x[3 * n + 2];

    const int r = HRES[li];
    float wx[2], wy[2], wz[2];
    unsigned ix, iy, iz;
    trilinear_setup(px, r, wx, &ix);
    trilinear_setup(py, r, wy, &iy);
    trilinear_setup(pz, r, wz, &iz);

    const float* __restrict__ tabf = params + 2u * (size_t)HOFF[li];

    const unsigned hy[2] = {iy * P1, (iy + 1u) * P1};
    const unsigned hz[2] = {iz * P2, (iz + 1u) * P2};

    float s0 = 0.0f, s1 = 0.0f;

    if ((ix & 1u) == 0u) {
        // even ix: corner pair (dx=0,dx=1) = {a, a^1} -> one aligned float4
#pragma unroll
        for (int p = 0; p < 4; ++p) {
            const unsigned dy = p & 1, dz = (p >> 1) & 1;
            const unsigned h = hy[dy] ^ hz[dz];
            const unsigned a = (ix ^ h) & HASH_MASK;      // corner dx=0
            const unsigned sw = a & 1u;                   // 1 -> pair stored (c1,c0)
            const f4a16 q = *(const f4a16*)(tabf + 2u * (a & ~1u));
            const float f0x = sw ? q.z : q.x;
            const float f0y = sw ? q.w : q.y;
            const float f1x = sw ? q.x : q.z;
            const float f1y = sw ? q.y : q.w;
            const float wyz = wy[dy] * wz[dz];
            const float wc0 = wx[0] * wyz;
            const float wc1 = wx[1] * wyz;
            s0 = fmaf(wc0, f0x, s0);
            s1 = fmaf(wc0, f0y, s1);
            s0 = fmaf(wc1, f1x, s0);
            s1 = fmaf(wc1, f1y, s1);
        }
    } else {
        const unsigned hx[2] = {ix, ix + 1u};
#pragma unroll
        for (int c = 0; c < 8; ++c) {
            const unsigned dx = c & 1, dy = (c >> 1) & 1, dz = (c >> 2) & 1;
            const unsigned idx = (hx[dx] ^ hy[dy] ^ hz[dz]) & HASH_MASK;
            const float2 f = *(const float2*)(tabf + 2u * idx);
            const float wc = (wx[dx] * wy[dy]) * wz[dz];
            s0 = fmaf(wc, f.x, s0);
            s1 = fmaf(wc, f.y, s1);
        }
    }

    ws[(size_t)li * N + n] = make_float2(s0, s1);
}

// ---------------- pass 2: dense levels (0..4) + merge + coalesced store -----
__global__ __launch_bounds__(256) void dense_merge_kernel(
    const float* __restrict__ x,
    const float* __restrict__ params,
    const float2* __restrict__ ws,   // [N_HASHED][N]
    float* __restrict__ out,
    int N)
{
    constexpr int      DRES[5] = {16, 23, 32, 46, 64};
    constexpr unsigned DOFF[5] = {0u, 4096u, 16264u, 49032u, 146368u};

    const int n = blockIdx.x * blockDim.x + threadIdx.x;
    if (n >= N) return;

    const float px = x[3 * n + 0];
    const float py = x[3 * n + 1];
    const float pz = x[3 * n + 2];

    float res[2 * N_LEVELS];

#pragma unroll
    for (int l = 0; l < 5; ++l) {
        const int r = DRES[l];
        float wx[2], wy[2], wz[2];
        unsigned ix, iy, iz;
        trilinear_setup(px, r, wx, &ix);
        trilinear_setup(py, r, wy, &iy);
        trilinear_setup(pz, r, wz, &iz);

        const float* __restrict__ tabf = params + 2u * (size_t)DOFF[l];
        const unsigned rr = (unsigned)(r * r);
        const unsigned base = ix + iy * (unsigned)r + iz * rr;

        float s0 = 0.0f, s1 = 0.0f;
#pragma unroll
        for (int p = 0; p < 4; ++p) {
            const unsigned dy = p & 1, dz = (p >> 1) & 1;
            const unsigned idx = base + dy * (unsigned)r + dz * rr;  // dx=0; dx=1 is idx+1
            const f4a8 q = *(const f4a8*)(tabf + 2u * idx);          // {c0.x,c0.y,c1.x,c1.y}
            const float wyz = wy[dy] * wz[dz];
            const float wc0 = wx[0] * wyz;
            const float wc1 = wx[1] * wyz;
            s0 = fmaf(wc0, q.x, s0);
            s1 = fmaf(wc0, q.y, s1);
            s0 = fmaf(wc1, q.z, s0);
            s1 = fmaf(wc1, q.w, s1);
        }
        res[2 * l + 0] = s0;
        res[2 * l + 1] = s1;
    }

#pragma unroll
    for (int li = 0; li < N_HASHED; ++li) {
        float2 f = ws[(size_t)li * N + n];    // coalesced: stride-8B in n
        res[2 * (5 + li) + 0] = f.x;
        res[2 * (5 + li) + 1] = f.y;
    }

    float4* __restrict__ o4 = (float4*)(out + (size_t)n * 24);
#pragma unroll
    for (int k = 0; k < 6; ++k) {
        float4 v;
        v.x = res[4 * k + 0];
        v.y = res[4 * k + 1];
        v.z = res[4 * k + 2];
        v.w = res[4 * k + 3];
        o4[k] = v;
    }
}

// ---------------- fallback: fused single kernel -----------------------------
__global__ __launch_bounds__(256) void grid_encode_fused_kernel(
    const float* __restrict__ x,
    const float* __restrict__ params,
    float* __restrict__ out,
    int N)
{
    int n = blockIdx.x * blockDim.x + threadIdx.x;
    if (n >= N) return;

    const float px = x[3 * n + 0];
    const float py = x[3 * n + 1];
    const float pz = x[3 * n + 2];

    constexpr int   RES[N_LEVELS]    = {16, 23, 32, 46, 64, 92, 128, 184, 256, 368, 512, 736};
    constexpr unsigned OFF[N_LEVELS] = {0u, 4096u, 16264u, 49032u, 146368u, 408512u,
                                        932800u, 1457088u, 1981376u, 2505664u, 3029952u, 3554240u};
    constexpr unsigned HASH_MASK = 524287u;
    constexpr unsigned P1 = 2654435761u;
    constexpr unsigned P2 = 805459861u;

    float res[2 * N_LEVELS];

#pragma unroll
    for (int l = 0; l < N_LEVELS; ++l) {
        const int r = RES[l];
        float wx[2], wy[2], wz[2];
        unsigned ix, iy, iz;
        trilinear_setup(px, r, wx, &ix);
        trilinear_setup(py, r, wy, &iy);
        trilinear_setup(pz, r, wz, &iz);

        const float2* __restrict__ tab = (const float2*)params + OFF[l];
        float s0 = 0.0f, s1 = 0.0f;

        const bool dense = ((long long)r * r * r) <= (long long)524288;
        if (dense) {
            const unsigned rr = (unsigned)(r * r);
            const unsigned base = ix + iy * (unsigned)r + iz * rr;
#pragma unroll
            for (int c = 0; c < 8; ++c) {
                const unsigned dx = c & 1, dy = (c >> 1) & 1, dz = (c >> 2) & 1;
                const unsigned idx = base + dx + dy * (unsigned)r + dz * rr;
                float2 f = tab[idx];
                float wc = (wx[dx] * wy[dy]) * wz[dz];
                s0 = fmaf(wc, f.x, s0);
                s1 = fmaf(wc, f.y, s1);
            }
        } else {
            const unsigned hx[2] = {ix, ix + 1u};
            const unsigned hy[2] = {iy * P1, (iy + 1u) * P1};
            const unsigned hz[2] = {iz * P2, (iz + 1u) * P2};
#pragma unroll
            for (int c = 0; c < 8; ++c) {
                const unsigned dx = c & 1, dy = (c >> 1) & 1, dz = (c >> 2) & 1;
                const unsigned idx = (hx[dx] ^ hy[dy] ^ hz[dz]) & HASH_MASK;
                float2 f = tab[idx];
                float wc = (wx[dx] * wy[dy]) * wz[dz];
                s0 = fmaf(wc, f.x, s0);
                s1 = fmaf(wc, f.y, s1);
            }
        }
        res[2 * l + 0] = s0;
        res[2 * l + 1] = s1;
    }

    float4* __restrict__ o4 = (float4*)(out + (size_t)n * 24);
#pragma unroll
    for (int k = 0; k < 6; ++k) {
        float4 v;
        v.x = res[4 * k + 0];
        v.y = res[4 * k + 1];
        v.z = res[4 * k + 2];
        v.w = res[4 * k + 3];
        o4[k] = v;
    }
}

extern "C" void kernel_launch(void* const* d_in, const int* in_sizes, int n_in,
                              void* d_out, int out_size, void* d_ws, size_t ws_size,
                              hipStream_t stream) {
    const float* x      = (const float*)d_in[0];
    const float* params = (const float*)d_in[1];
    float* out          = (float*)d_out;

    const int N = in_sizes[0] / 3;  // 1<<20
    const int block = 256;
    const int gx = (N + block - 1) / block;

    const size_t ws_needed = (size_t)N_HASHED * (size_t)N * sizeof(float2);  // 56 MB

    if (ws_size >= ws_needed) {
        float2* ws = (float2*)d_ws;
        dim3 grid1(gx, N_HASHED, 1);
        hashed_levels_kernel<<<grid1, block, 0, stream>>>(x, params, ws, N);
        dense_merge_kernel<<<gx, block, 0, stream>>>(x, params, ws, out, N);
    } else {
        grid_encode_fused_kernel<<<gx, block, 0, stream>>>(x, params, out, N);
    }
}